// Round 1
// baseline (585.711 us; speedup 1.0000x reference)
//
#include <hip/hip_runtime.h>
#include <stdint.h>

#define S_LEN 2048
#define BATCH 2
#define NH 16
#define NKV 4
#define HD 128
#define HID 2048
#define MROWS (BATCH * S_LEN)  // 4096
#define QBLK 64                // flash_attn Q-tile rows per block

typedef unsigned short u16;
typedef __attribute__((ext_vector_type(8))) short frag_ab;
typedef __attribute__((ext_vector_type(4))) float frag_cd;

static __device__ __forceinline__ float bf2f(u16 v) {
    union { unsigned u; float f; } t; t.u = ((unsigned)v) << 16; return t.f;
}
static __device__ __forceinline__ u16 f2bf(float f) {
    union { float f; unsigned u; } t; t.f = f;
    unsigned r = t.u + 0x7fffu + ((t.u >> 16) & 1u);  // RNE
    return (u16)(r >> 16);
}
// async global->LDS, 16B per lane; LDS dest = wave-uniform base + lane*16
static __device__ __forceinline__ void load_lds16(const u16* g, u16* l) {
    __builtin_amdgcn_global_load_lds((const __attribute__((address_space(1))) void*)g,
                                     (__attribute__((address_space(3))) void*)l, 16, 0, 0);
}

// ---------------- fp32 -> bf16 bulk convert ----------------
__global__ __launch_bounds__(256) void conv_f32_bf16(const float* __restrict__ src,
                                                     u16* __restrict__ dst, int n4) {
    int i = blockIdx.x * 256 + threadIdx.x;
    if (i >= n4) return;
    float4 v = ((const float4*)src)[i];
    ushort4 o;
    o.x = f2bf(v.x); o.y = f2bf(v.y); o.z = f2bf(v.z); o.w = f2bf(v.w);
    ((ushort4*)dst)[i] = o;
}

// ---------------- C = A (MxK) * B^T (B stored [N][K]), fp32 out ----------------
// 128x128 tile, 4 waves x (4x4) 16x16x32 MFMA, BK=32, global_load_lds width=16
// staging (m97 ladder step 3).
__global__ __launch_bounds__(256) void gemm_bt(const u16* __restrict__ A, const u16* __restrict__ B,
                                               float* __restrict__ C, int M, int N, int K) {
    __shared__ u16 As[128 * 32];
    __shared__ u16 Bs[128 * 32];
    const int tid = threadIdx.x;
    const int wave = tid >> 6, lane = tid & 63;
    const int quad = lane >> 4, lr = lane & 15;
    const int wm = (wave & 1) * 64, wn = (wave >> 1) * 64;
    const long bm = (long)blockIdx.x * 128, bn = (long)blockIdx.y * 128;
    // staging: chunk c = issue*256 + wave*64 + lane; row=c>>2, col16=c&3
    const int srow = (wave << 4) + (lane >> 2);   // + issue*64
    const int scol = (lane & 3) * 8;
    const u16* Ag = A + (bm + srow) * (long)K + scol;
    const u16* Bg = B + (bn + srow) * (long)K + scol;
    u16* AsW = As + wave * 512;                    // + issue*2048 (u16)
    u16* BsW = Bs + wave * 512;

    frag_cd acc[4][4];
#pragma unroll
    for (int i = 0; i < 4; i++)
#pragma unroll
        for (int j = 0; j < 4; j++) acc[i][j] = (frag_cd){0.f, 0.f, 0.f, 0.f};

    for (int k0 = 0; k0 < K; k0 += 32) {
        __syncthreads();  // prev iter's LDS readers done
        load_lds16(Ag + k0, AsW);
        load_lds16(Ag + (long)64 * K + k0, AsW + 2048);
        load_lds16(Bg + k0, BsW);
        load_lds16(Bg + (long)64 * K + k0, BsW + 2048);
        __syncthreads();  // staging complete (vmcnt(0) drained by barrier)
        frag_ab af[4], bfr[4];
#pragma unroll
        for (int i = 0; i < 4; i++) af[i] = *(const frag_ab*)(As + (wm + i * 16 + lr) * 32 + quad * 8);
#pragma unroll
        for (int j = 0; j < 4; j++) bfr[j] = *(const frag_ab*)(Bs + (wn + j * 16 + lr) * 32 + quad * 8);
#pragma unroll
        for (int i = 0; i < 4; i++)
#pragma unroll
            for (int j = 0; j < 4; j++)
                acc[i][j] = __builtin_amdgcn_mfma_f32_16x16x32_bf16(af[i], bfr[j], acc[i][j], 0, 0, 0);
    }
    // C/D layout: col = lane&15, row = (lane>>4)*4 + reg   [measured m89/m91]
#pragma unroll
    for (int i = 0; i < 4; i++)
#pragma unroll
        for (int j = 0; j < 4; j++)
#pragma unroll
            for (int r = 0; r < 4; r++) {
                long row = bm + wm + i * 16 + quad * 4 + r;
                long col = bn + wn + j * 16 + lr;
                C[row * N + col] = acc[i][j][r];
            }
}

// ---------------- RMSNorm(head_dim) + RoPE, fp32 in -> bf16 out [b][h][s][d] ----------------
__global__ __launch_bounds__(256) void rope_norm(const float* __restrict__ src, u16* __restrict__ dst,
                                                 const float* __restrict__ nw, int nh, int stride, int coff) {
    const int m = blockIdx.x;                 // 0..4095 (b*S+s)
    const int wave = threadIdx.x >> 6, lane = threadIdx.x & 63;
    const int s = m & (S_LEN - 1), b = m >> 11;
    const int d0 = 2 * lane;
    const float w0 = nw[d0], w1 = nw[d0 + 1];
    const int i0 = d0 & 63;
    const float lnt_over = 13.122363377404328f / 64.f;  // ln(500000)/64
    float inv0 = expf(-(float)i0 * lnt_over);
    float inv1 = expf(-(float)(i0 + 1) * lnt_over);
    float c0 = cosf((float)s * inv0), sn0 = sinf((float)s * inv0);
    float c1 = cosf((float)s * inv1), sn1 = sinf((float)s * inv1);
    for (int h = wave; h < nh; h += 4) {
        float2 x = *(const float2*)(src + (long)m * stride + coff + h * HD + d0);
        float ss = x.x * x.x + x.y * x.y;
#pragma unroll
        for (int off = 1; off < 64; off <<= 1) ss += __shfl_xor(ss, off);
        float rs = rsqrtf(ss * (1.f / HD) + 1e-5f);
        float xn0 = x.x * rs * w0;
        float xn1 = x.y * rs * w1;
        float p0 = __shfl_xor(xn0, 32);
        float p1 = __shfl_xor(xn1, 32);
        float r0 = (lane < 32) ? -p0 : p0;   // rotate_half
        float r1 = (lane < 32) ? -p1 : p1;
        float y0 = xn0 * c0 + r0 * sn0;
        float y1 = xn1 * c1 + r1 * sn1;
        unsigned outw = (unsigned)f2bf(y0) | ((unsigned)f2bf(y1) << 16);
        *(unsigned*)(dst + (((long)(b * nh + h) * S_LEN + s) * HD + d0)) = outw;
    }
}

// ---------------- V: fp32 gout [m][coff+kh*128+d] -> bf16 TRANSPOSED [b][kh][d][s] ----------------
__global__ __launch_bounds__(256) void pack_vt(const float* __restrict__ src, u16* __restrict__ dst,
                                               int stride, int coff) {
    __shared__ u16 t[128 * 72];  // [d][s], rows padded 64->72
    const int tid = threadIdx.x;
    const int st = blockIdx.x & 31;
    const int kh = (blockIdx.x >> 5) & 3;
    const int b = blockIdx.x >> 7;
    const long m0 = (long)b * S_LEN + st * 64;
#pragma unroll
    for (int c = 0; c < 8; c++) {
        int idx = c * 256 + tid;           // 0..2047 float4s
        int r = idx >> 5, cg = idx & 31;   // s-row 0..63, col-group 0..31
        float4 v = *(const float4*)(src + (m0 + r) * stride + coff + kh * HD + cg * 4);
        int col = cg * 4;
        t[(col + 0) * 72 + r] = f2bf(v.x);
        t[(col + 1) * 72 + r] = f2bf(v.y);
        t[(col + 2) * 72 + r] = f2bf(v.z);
        t[(col + 3) * 72 + r] = f2bf(v.w);
    }
    __syncthreads();
    const int d = tid >> 1, sh = (tid & 1) * 32;
    u16* dp = dst + ((long)(b * NKV + kh) * HD + d) * S_LEN + st * 64 + sh;
    const u16* tp = &t[d * 72 + sh];
    *(uint4*)(dp + 0)  = *(const uint4*)(tp + 0);
    *(uint4*)(dp + 8)  = *(const uint4*)(tp + 8);
    *(uint4*)(dp + 16) = *(const uint4*)(tp + 16);
    *(uint4*)(dp + 24) = *(const uint4*)(tp + 24);
}

// ---------------- MFMA flash attention v4 ----------------
// Occupancy rework: 64-row Q-tiles, one tile per block (grid 1024 = 4 blocks/CU),
// each wave owns 16 rows -> per-wave state halves vs v3, __launch_bounds__(256,4)
// targets 4 waves/SIMD. Causal pairing replaced by a dispatch-balanced tile map:
// co-scheduled blocks {i, i+256, i+512, i+768} get tiles {16+j, 31-j, j, 15-j}
// (j = (i&255)>>5), constant 66 work-units per CU slot under round-robin
// dispatch; if only 3 waves/SIMD fit, the 4th (refill) group is anti-correlated
// with resident load (residents 50+j, refill 16-j).
// K/V fragments read DIRECT from global (L1/L2-resident, broadcast across waves);
// only P's C->A round-trip uses per-wave LDS (stride 80 u16, 16B-aligned rows).
__global__ __launch_bounds__(256, 4) void flash_attn(const u16* __restrict__ Q, const u16* __restrict__ K,
                                                     const u16* __restrict__ Vt, u16* __restrict__ O) {
    __shared__ u16 Pls[4 * 16 * 80];
    const int tid = threadIdx.x;
    const int wave = tid >> 6, lane = tid & 63;
    const int quad = lane >> 4, lr = lane & 15;
    const int c = blockIdx.x & 255;
    const int g = blockIdx.x >> 8;        // dispatch group 0..3
    const int j = c >> 5;                 // CU slot class 0..7
    const int bh = c & 31;
    const int h = bh & 15, b = bh >> 4;
    const int t = (g == 0) ? (16 + j) : (g == 1) ? (31 - j) : (g == 2) ? j : (15 - j);
    const int kh = h >> 2;
    const float scale = 0.08838834764831845f;  // 1/sqrt(128)
    const u16* Qb = Q + ((long)(b * NH + h) * S_LEN) * HD;
    const u16* Kb = K + ((long)(b * NKV + kh) * S_LEN) * HD;
    const u16* Vb = Vt + ((long)(b * NKV + kh) * HD) * S_LEN;
    const int pbase = wave * 16 * 80;

    const int q0 = t * QBLK;
    const int qr0 = q0 + wave * 16;       // this wave's first Q row

    frag_ab qf[4];
#pragma unroll
    for (int ks = 0; ks < 4; ks++)
        qf[ks] = *(const frag_ab*)(Qb + (long)(qr0 + lr) * HD + ks * 32 + quad * 8);

    frag_cd oa[8];
    float m_i[4], l_i[4];
#pragma unroll
    for (int dt = 0; dt < 8; dt++) oa[dt] = (frag_cd){0.f, 0.f, 0.f, 0.f};
#pragma unroll
    for (int r = 0; r < 4; r++) { m_i[r] = -3e38f; l_i[r] = 0.f; }

    const int nkt = t + 1;                // keys [0, 64*(t+1))
    for (int kt = 0; kt < nkt; kt++) {
        const int j0 = kt * 64;
        // S = Q K^T  (kf direct from global K[key][d])
        frag_cd sa[4];
#pragma unroll
        for (int nt = 0; nt < 4; nt++) sa[nt] = (frag_cd){0.f, 0.f, 0.f, 0.f};
#pragma unroll
        for (int nt = 0; nt < 4; nt++) {
            frag_ab kf[4];
#pragma unroll
            for (int ks = 0; ks < 4; ks++)
                kf[ks] = *(const frag_ab*)(Kb + (long)(j0 + nt * 16 + lr) * HD + ks * 32 + quad * 8);
#pragma unroll
            for (int ks = 0; ks < 4; ks++)
                sa[nt] = __builtin_amdgcn_mfma_f32_16x16x32_bf16(qf[ks], kf[ks], sa[nt], 0, 0, 0);
        }

        const bool need_mask = (j0 + 63) > qr0;
        // online softmax (C-layout: row=quad*4+r, col=lr)
        float mrow[4] = {-3e38f, -3e38f, -3e38f, -3e38f};
#pragma unroll
        for (int nt = 0; nt < 4; nt++) {
            int key = j0 + nt * 16 + lr;
#pragma unroll
            for (int r = 0; r < 4; r++) {
                int qrow = qr0 + quad * 4 + r;
                float v = sa[nt][r] * scale;
                if (need_mask) v = (key <= qrow) ? v : -3e38f;
                sa[nt][r] = v;
                mrow[r] = fmaxf(mrow[r], v);
            }
        }
#pragma unroll
        for (int off = 1; off < 16; off <<= 1)
#pragma unroll
            for (int r = 0; r < 4; r++) mrow[r] = fmaxf(mrow[r], __shfl_xor(mrow[r], off));
        float rs[4];
#pragma unroll
        for (int r = 0; r < 4; r++) {
            float mn = fmaxf(m_i[r], mrow[r]);
            float alpha = __expf(m_i[r] - mn);
            m_i[r] = mn;
            l_i[r] *= alpha;
            rs[r] = 0.f;
#pragma unroll
            for (int dt = 0; dt < 8; dt++) oa[dt][r] *= alpha;
        }
#pragma unroll
        for (int nt = 0; nt < 4; nt++)
#pragma unroll
            for (int r = 0; r < 4; r++) {
                float pw = __expf(sa[nt][r] - m_i[r]);
                rs[r] += pw;
                Pls[pbase + (quad * 4 + r) * 80 + nt * 16 + lr] = f2bf(pw);
            }
#pragma unroll
        for (int off = 1; off < 16; off <<= 1)
#pragma unroll
            for (int r = 0; r < 4; r++) rs[r] += __shfl_xor(rs[r], off);
#pragma unroll
        for (int r = 0; r < 4; r++) l_i[r] += rs[r];

        // O += P V  (pf via per-wave LDS; vf direct from global Vt[d][s])
#pragma unroll
        for (int ks = 0; ks < 2; ks++) {
            frag_ab pf = *(const frag_ab*)&Pls[pbase + lr * 80 + ks * 32 + quad * 8];
            frag_ab vf[8];
#pragma unroll
            for (int dt = 0; dt < 8; dt++)
                vf[dt] = *(const frag_ab*)(Vb + (long)(dt * 16 + lr) * S_LEN + j0 + ks * 32 + quad * 8);
#pragma unroll
            for (int dt = 0; dt < 8; dt++)
                oa[dt] = __builtin_amdgcn_mfma_f32_16x16x32_bf16(pf, vf[dt], oa[dt], 0, 0, 0);
        }
    }

    // epilogue: O[b*S+s][h*128+d] bf16
    float inv[4];
#pragma unroll
    for (int r = 0; r < 4; r++) inv[r] = 1.f / l_i[r];
#pragma unroll
    for (int dt = 0; dt < 8; dt++)
#pragma unroll
        for (int r = 0; r < 4; r++) {
            int s = qr0 + quad * 4 + r;
            O[((long)b * S_LEN + s) * (NH * HD) + h * HD + dt * 16 + lr] =
                f2bf(oa[dt][r] * inv[r]);
        }
}

extern "C" void kernel_launch(void* const* d_in, const int* in_sizes, int n_in,
                              void* d_out, int out_size, void* d_ws, size_t ws_size,
                              hipStream_t stream) {
    const float* hs  = (const float*)d_in[0];
    const float* q_w = (const float*)d_in[1];
    const float* k_w = (const float*)d_in[2];
    const float* v_w = (const float*)d_in[3];
    const float* o_w = (const float*)d_in[4];
    const float* qnw = (const float*)d_in[5];
    const float* knw = (const float*)d_in[6];
    float* out = (float*)d_out;

    // Workspace (72 MiB, live ranges stream-serialized & disjoint):
    //   [ 0,16M) hs_bf : hidden bf16; later attn-out bf16
    //   [16,24M) wbuf  : weights bf16 (Q 8M; then KV 4M; then O 8M)
    //   [24,56M) gout  : fp32 GEMM out (Q all 32M; KV uses [24,40) only)
    //   [40,44M) Kr    : bf16 [b][4][s][128]
    //   [44,48M) Vt    : bf16 [b][4][d][s] transposed
    //   [56,72M) Qr    : bf16 [b][16][s][128]
    char* ws = (char*)d_ws;
    u16* hs_bf  = (u16*)(ws);
    u16* wbuf   = (u16*)(ws + (16ul << 20));
    float* gout = (float*)(ws + (24ul << 20));
    u16* Kr     = (u16*)(ws + (40ul << 20));
    u16* Vt     = (u16*)(ws + (44ul << 20));
    u16* Qr     = (u16*)(ws + (56ul << 20));
    (void)ws_size; (void)in_sizes; (void)n_in; (void)out_size;

    // hidden -> bf16
    conv_f32_bf16<<<(MROWS * HID / 4 + 255) / 256, 256, 0, stream>>>(hs, hs_bf, MROWS * HID / 4);

    // Q = hs @ q_w^T ; rmsnorm + rope
    conv_f32_bf16<<<(HID * HID / 4 + 255) / 256, 256, 0, stream>>>(q_w, wbuf, HID * HID / 4);
    dim3 gq(MROWS / 128, HID / 128);
    gemm_bt<<<gq, 256, 0, stream>>>(hs_bf, wbuf, gout, MROWS, HID, HID);
    rope_norm<<<MROWS, 256, 0, stream>>>(gout, Qr, qnw, NH, HID, 0);

    // K|V fused projection: wbuf rows [0,512)=k_w, [512,1024)=v_w; N=1024
    conv_f32_bf16<<<(NKV * HD * HID / 4 + 255) / 256, 256, 0, stream>>>(k_w, wbuf, NKV * HD * HID / 4);
    conv_f32_bf16<<<(NKV * HD * HID / 4 + 255) / 256, 256, 0, stream>>>(v_w, wbuf + NKV * HD * HID, NKV * HD * HID / 4);
    dim3 gkv(MROWS / 128, (2 * NKV * HD) / 128);
    gemm_bt<<<gkv, 256, 0, stream>>>(hs_bf, wbuf, gout, MROWS, 2 * NKV * HD, HID);
    rope_norm<<<MROWS, 256, 0, stream>>>(gout, Kr, knw, NKV, 2 * NKV * HD, 0);
    pack_vt<<<BATCH * NKV * (S_LEN / 64), 256, 0, stream>>>(gout, Vt, 2 * NKV * HD, NKV * HD);

    // attention -> hs_bf  (grid = 32 tiles x 16 h x 2 b = 1024)
    flash_attn<<<(S_LEN / QBLK) * NH * BATCH, 256, 0, stream>>>(Qr, Kr, Vt, hs_bf);

    // out = attn @ o_w^T
    conv_f32_bf16<<<(HID * HID / 4 + 255) / 256, 256, 0, stream>>>(o_w, wbuf, HID * HID / 4);
    gemm_bt<<<gq, 256, 0, stream>>>(hs_bf, wbuf, out, MROWS, HID, HID);
}

// Round 2
// 505.899 us; speedup vs baseline: 1.1578x; 1.1578x over previous
//
#include <hip/hip_runtime.h>
#include <stdint.h>

#define S_LEN 2048
#define BATCH 2
#define NH 16
#define NKV 4
#define HD 128
#define HID 2048
#define MROWS (BATCH * S_LEN)  // 4096

typedef unsigned short u16;
typedef __attribute__((ext_vector_type(8))) short frag_ab;
typedef __attribute__((ext_vector_type(4))) float frag_cd;

static __device__ __forceinline__ float bf2f(u16 v) {
    union { unsigned u; float f; } t; t.u = ((unsigned)v) << 16; return t.f;
}
static __device__ __forceinline__ u16 f2bf(float f) {
    union { float f; unsigned u; } t; t.f = f;
    unsigned r = t.u + 0x7fffu + ((t.u >> 16) & 1u);  // RNE
    return (u16)(r >> 16);
}
// async global->LDS, 16B per lane; LDS dest = wave-uniform base + lane*16
static __device__ __forceinline__ void load_lds16(const u16* g, u16* l) {
    __builtin_amdgcn_global_load_lds((const __attribute__((address_space(1))) void*)g,
                                     (__attribute__((address_space(3))) void*)l, 16, 0, 0);
}

// ---------------- fp32 -> bf16 bulk convert ----------------
__global__ __launch_bounds__(256) void conv_f32_bf16(const float* __restrict__ src,
                                                     u16* __restrict__ dst, int n4) {
    int i = blockIdx.x * 256 + threadIdx.x;
    if (i >= n4) return;
    float4 v = ((const float4*)src)[i];
    ushort4 o;
    o.x = f2bf(v.x); o.y = f2bf(v.y); o.z = f2bf(v.z); o.w = f2bf(v.w);
    ((ushort4*)dst)[i] = o;
}

// ---------------- C = A (MxK) * B^T (B stored [N][K]), fp32 out ----------------
// 128x128 tile, 4 waves x (4x4) 16x16x32 MFMA, BK=32, global_load_lds width=16
// staging (m97 ladder step 3).
__global__ __launch_bounds__(256) void gemm_bt(const u16* __restrict__ A, const u16* __restrict__ B,
                                               float* __restrict__ C, int M, int N, int K) {
    __shared__ u16 As[128 * 32];
    __shared__ u16 Bs[128 * 32];
    const int tid = threadIdx.x;
    const int wave = tid >> 6, lane = tid & 63;
    const int quad = lane >> 4, lr = lane & 15;
    const int wm = (wave & 1) * 64, wn = (wave >> 1) * 64;
    const long bm = (long)blockIdx.x * 128, bn = (long)blockIdx.y * 128;
    // staging: chunk c = issue*256 + wave*64 + lane; row=c>>2, col16=c&3
    const int srow = (wave << 4) + (lane >> 2);   // + issue*64
    const int scol = (lane & 3) * 8;
    const u16* Ag = A + (bm + srow) * (long)K + scol;
    const u16* Bg = B + (bn + srow) * (long)K + scol;
    u16* AsW = As + wave * 512;                    // + issue*2048 (u16)
    u16* BsW = Bs + wave * 512;

    frag_cd acc[4][4];
#pragma unroll
    for (int i = 0; i < 4; i++)
#pragma unroll
        for (int j = 0; j < 4; j++) acc[i][j] = (frag_cd){0.f, 0.f, 0.f, 0.f};

    for (int k0 = 0; k0 < K; k0 += 32) {
        __syncthreads();  // prev iter's LDS readers done
        load_lds16(Ag + k0, AsW);
        load_lds16(Ag + (long)64 * K + k0, AsW + 2048);
        load_lds16(Bg + k0, BsW);
        load_lds16(Bg + (long)64 * K + k0, BsW + 2048);
        __syncthreads();  // staging complete (vmcnt(0) drained by barrier)
        frag_ab af[4], bfr[4];
#pragma unroll
        for (int i = 0; i < 4; i++) af[i] = *(const frag_ab*)(As + (wm + i * 16 + lr) * 32 + quad * 8);
#pragma unroll
        for (int j = 0; j < 4; j++) bfr[j] = *(const frag_ab*)(Bs + (wn + j * 16 + lr) * 32 + quad * 8);
#pragma unroll
        for (int i = 0; i < 4; i++)
#pragma unroll
            for (int j = 0; j < 4; j++)
                acc[i][j] = __builtin_amdgcn_mfma_f32_16x16x32_bf16(af[i], bfr[j], acc[i][j], 0, 0, 0);
    }
    // C/D layout: col = lane&15, row = (lane>>4)*4 + reg   [measured m89/m91]
#pragma unroll
    for (int i = 0; i < 4; i++)
#pragma unroll
        for (int j = 0; j < 4; j++)
#pragma unroll
            for (int r = 0; r < 4; r++) {
                long row = bm + wm + i * 16 + quad * 4 + r;
                long col = bn + wn + j * 16 + lr;
                C[row * N + col] = acc[i][j][r];
            }
}

// ---------------- RMSNorm(head_dim) + RoPE, fp32 in -> bf16 out [b][h][s][d] ----------------
__global__ __launch_bounds__(256) void rope_norm(const float* __restrict__ src, u16* __restrict__ dst,
                                                 const float* __restrict__ nw, int nh, int stride, int coff) {
    const int m = blockIdx.x;                 // 0..4095 (b*S+s)
    const int wave = threadIdx.x >> 6, lane = threadIdx.x & 63;
    const int s = m & (S_LEN - 1), b = m >> 11;
    const int d0 = 2 * lane;
    const float w0 = nw[d0], w1 = nw[d0 + 1];
    const int i0 = d0 & 63;
    const float lnt_over = 13.122363377404328f / 64.f;  // ln(500000)/64
    float inv0 = expf(-(float)i0 * lnt_over);
    float inv1 = expf(-(float)(i0 + 1) * lnt_over);
    float c0 = cosf((float)s * inv0), sn0 = sinf((float)s * inv0);
    float c1 = cosf((float)s * inv1), sn1 = sinf((float)s * inv1);
    for (int h = wave; h < nh; h += 4) {
        float2 x = *(const float2*)(src + (long)m * stride + coff + h * HD + d0);
        float ss = x.x * x.x + x.y * x.y;
#pragma unroll
        for (int off = 1; off < 64; off <<= 1) ss += __shfl_xor(ss, off);
        float rs = rsqrtf(ss * (1.f / HD) + 1e-5f);
        float xn0 = x.x * rs * w0;
        float xn1 = x.y * rs * w1;
        float p0 = __shfl_xor(xn0, 32);
        float p1 = __shfl_xor(xn1, 32);
        float r0 = (lane < 32) ? -p0 : p0;   // rotate_half
        float r1 = (lane < 32) ? -p1 : p1;
        float y0 = xn0 * c0 + r0 * sn0;
        float y1 = xn1 * c1 + r1 * sn1;
        unsigned outw = (unsigned)f2bf(y0) | ((unsigned)f2bf(y1) << 16);
        *(unsigned*)(dst + (((long)(b * nh + h) * S_LEN + s) * HD + d0)) = outw;
    }
}

// ---------------- V: fp32 gout [m][coff+kh*128+d] -> bf16 TRANSPOSED [b][kh][d][s] ----------------
__global__ __launch_bounds__(256) void pack_vt(const float* __restrict__ src, u16* __restrict__ dst,
                                               int stride, int coff) {
    __shared__ u16 t[128 * 72];  // [d][s], rows padded 64->72
    const int tid = threadIdx.x;
    const int st = blockIdx.x & 31;
    const int kh = (blockIdx.x >> 5) & 3;
    const int b = blockIdx.x >> 7;
    const long m0 = (long)b * S_LEN + st * 64;
#pragma unroll
    for (int c = 0; c < 8; c++) {
        int idx = c * 256 + tid;           // 0..2047 float4s
        int r = idx >> 5, cg = idx & 31;   // s-row 0..63, col-group 0..31
        float4 v = *(const float4*)(src + (m0 + r) * stride + coff + kh * HD + cg * 4);
        int col = cg * 4;
        t[(col + 0) * 72 + r] = f2bf(v.x);
        t[(col + 1) * 72 + r] = f2bf(v.y);
        t[(col + 2) * 72 + r] = f2bf(v.z);
        t[(col + 3) * 72 + r] = f2bf(v.w);
    }
    __syncthreads();
    const int d = tid >> 1, sh = (tid & 1) * 32;
    u16* dp = dst + ((long)(b * NKV + kh) * HD + d) * S_LEN + st * 64 + sh;
    const u16* tp = &t[d * 72 + sh];
    *(uint4*)(dp + 0)  = *(const uint4*)(tp + 0);
    *(uint4*)(dp + 8)  = *(const uint4*)(tp + 8);
    *(uint4*)(dp + 16) = *(const uint4*)(tp + 16);
    *(uint4*)(dp + 24) = *(const uint4*)(tp + 24);
}

// ---------------- MFMA flash attention v5 ----------------
// v3 per-wave structure (32 rows/wave, 2 mt sub-tiles -> K/V fragment loads
// amortized over 2 MFMAs; ~180 VGPR, NO min-waves launch bound so no spills)
// but decomposed as 2-wave blocks / 64-row Q-tiles / grid 1024:
// 4 blocks/CU x 2 waves = 8 waves/CU = 2 waves/SIMD (v3 had 1 wave/SIMD and
// ~80% exposed-latency stall; TLP doubles). Work balance via bijective tile
// map: co-scheduled groups g=0..3 get t = {16+j, 31-j, j, 15-j} (j = CU slot
// class), constant 66 kt per slot. K/V fragments direct from global (L1/L2
// resident); P's C->A round-trip via per-wave LDS (stride 80 u16).
__global__ __launch_bounds__(128) void flash_attn(const u16* __restrict__ Q, const u16* __restrict__ K,
                                                  const u16* __restrict__ Vt, u16* __restrict__ O) {
    __shared__ u16 Pls[2 * 32 * 80];
    const int tid = threadIdx.x;
    const int wave = tid >> 6, lane = tid & 63;
    const int quad = lane >> 4, lr = lane & 15;
    const int c = blockIdx.x & 255;
    const int g = blockIdx.x >> 8;        // dispatch group 0..3
    const int j = c >> 5;                 // CU slot class 0..7
    const int bh = c & 31;
    const int h = bh & 15, b = bh >> 4;
    const int t = (g == 0) ? (16 + j) : (g == 1) ? (31 - j) : (g == 2) ? j : (15 - j);
    const int kh = h >> 2;
    const float scale = 0.08838834764831845f;  // 1/sqrt(128)
    const u16* Qb = Q + ((long)(b * NH + h) * S_LEN) * HD;
    const u16* Kb = K + ((long)(b * NKV + kh) * S_LEN) * HD;
    const u16* Vb = Vt + ((long)(b * NKV + kh) * HD) * S_LEN;
    const int pbase = wave * 32 * 80;

    const int q0 = t * 64;
    frag_ab qf[2][4];
#pragma unroll
    for (int mt = 0; mt < 2; mt++) {
        int qrow = q0 + wave * 32 + mt * 16 + lr;
#pragma unroll
        for (int ks = 0; ks < 4; ks++)
            qf[mt][ks] = *(const frag_ab*)(Qb + (long)qrow * HD + ks * 32 + quad * 8);
    }
    frag_cd oa[2][8];
    float m_i[2][4], l_i[2][4];
#pragma unroll
    for (int mt = 0; mt < 2; mt++) {
#pragma unroll
        for (int dt = 0; dt < 8; dt++) oa[mt][dt] = (frag_cd){0.f, 0.f, 0.f, 0.f};
#pragma unroll
        for (int r = 0; r < 4; r++) { m_i[mt][r] = -3e38f; l_i[mt][r] = 0.f; }
    }
    const int nkt = t + 1;                // keys [0, 64*(t+1))

    for (int kt = 0; kt < nkt; kt++) {
        const int j0 = kt * 64;
        // S = Q K^T  (kf direct from global K[key][d])
        frag_cd sa[2][4];
#pragma unroll
        for (int mt = 0; mt < 2; mt++)
#pragma unroll
            for (int nt = 0; nt < 4; nt++) sa[mt][nt] = (frag_cd){0.f, 0.f, 0.f, 0.f};
#pragma unroll
        for (int nt = 0; nt < 4; nt++) {
            frag_ab kf[4];
#pragma unroll
            for (int ks = 0; ks < 4; ks++)
                kf[ks] = *(const frag_ab*)(Kb + (long)(j0 + nt * 16 + lr) * HD + ks * 32 + quad * 8);
#pragma unroll
            for (int mt = 0; mt < 2; mt++)
#pragma unroll
                for (int ks = 0; ks < 4; ks++)
                    sa[mt][nt] = __builtin_amdgcn_mfma_f32_16x16x32_bf16(qf[mt][ks], kf[ks], sa[mt][nt], 0, 0, 0);
        }

        const bool need_mask = (j0 + 63) > (q0 + wave * 32);
        // online softmax (C-layout: row=quad*4+r, col=lr)
#pragma unroll
        for (int mt = 0; mt < 2; mt++) {
            float mrow[4] = {-3e38f, -3e38f, -3e38f, -3e38f};
#pragma unroll
            for (int nt = 0; nt < 4; nt++) {
                int key = j0 + nt * 16 + lr;
#pragma unroll
                for (int r = 0; r < 4; r++) {
                    int qrow = q0 + wave * 32 + mt * 16 + quad * 4 + r;
                    float v = sa[mt][nt][r] * scale;
                    if (need_mask) v = (key <= qrow) ? v : -3e38f;
                    sa[mt][nt][r] = v;
                    mrow[r] = fmaxf(mrow[r], v);
                }
            }
#pragma unroll
            for (int off = 1; off < 16; off <<= 1)
#pragma unroll
                for (int r = 0; r < 4; r++) mrow[r] = fmaxf(mrow[r], __shfl_xor(mrow[r], off));
            float rs[4];
#pragma unroll
            for (int r = 0; r < 4; r++) {
                float mn = fmaxf(m_i[mt][r], mrow[r]);
                float alpha = __expf(m_i[mt][r] - mn);
                m_i[mt][r] = mn;
                l_i[mt][r] *= alpha;
                rs[r] = 0.f;
#pragma unroll
                for (int dt = 0; dt < 8; dt++) oa[mt][dt][r] *= alpha;
            }
#pragma unroll
            for (int nt = 0; nt < 4; nt++)
#pragma unroll
                for (int r = 0; r < 4; r++) {
                    float pw = __expf(sa[mt][nt][r] - m_i[mt][r]);
                    rs[r] += pw;
                    Pls[pbase + (mt * 16 + quad * 4 + r) * 80 + nt * 16 + lr] = f2bf(pw);
                }
#pragma unroll
            for (int off = 1; off < 16; off <<= 1)
#pragma unroll
                for (int r = 0; r < 4; r++) rs[r] += __shfl_xor(rs[r], off);
#pragma unroll
            for (int r = 0; r < 4; r++) l_i[mt][r] += rs[r];
        }

        // O += P V  (pf via per-wave LDS; vf direct from global Vt[d][s])
#pragma unroll
        for (int ks = 0; ks < 2; ks++) {
            frag_ab pf[2];
#pragma unroll
            for (int mt = 0; mt < 2; mt++)
                pf[mt] = *(const frag_ab*)&Pls[pbase + (mt * 16 + lr) * 80 + ks * 32 + quad * 8];
            frag_ab vf[8];
#pragma unroll
            for (int dt = 0; dt < 8; dt++)
                vf[dt] = *(const frag_ab*)(Vb + (long)(dt * 16 + lr) * S_LEN + j0 + ks * 32 + quad * 8);
#pragma unroll
            for (int dt = 0; dt < 8; dt++) {
                oa[0][dt] = __builtin_amdgcn_mfma_f32_16x16x32_bf16(pf[0], vf[dt], oa[0][dt], 0, 0, 0);
                oa[1][dt] = __builtin_amdgcn_mfma_f32_16x16x32_bf16(pf[1], vf[dt], oa[1][dt], 0, 0, 0);
            }
        }
    }

    // epilogue: O[b*S+s][h*128+d] bf16
#pragma unroll
    for (int mt = 0; mt < 2; mt++) {
        float inv[4];
#pragma unroll
        for (int r = 0; r < 4; r++) inv[r] = 1.f / l_i[mt][r];
#pragma unroll
        for (int dt = 0; dt < 8; dt++)
#pragma unroll
            for (int r = 0; r < 4; r++) {
                int s = q0 + wave * 32 + mt * 16 + quad * 4 + r;
                O[((long)b * S_LEN + s) * (NH * HD) + h * HD + dt * 16 + lr] =
                    f2bf(oa[mt][dt][r] * inv[r]);
            }
    }
}

extern "C" void kernel_launch(void* const* d_in, const int* in_sizes, int n_in,
                              void* d_out, int out_size, void* d_ws, size_t ws_size,
                              hipStream_t stream) {
    const float* hs  = (const float*)d_in[0];
    const float* q_w = (const float*)d_in[1];
    const float* k_w = (const float*)d_in[2];
    const float* v_w = (const float*)d_in[3];
    const float* o_w = (const float*)d_in[4];
    const float* qnw = (const float*)d_in[5];
    const float* knw = (const float*)d_in[6];
    float* out = (float*)d_out;

    // Workspace (72 MiB, live ranges stream-serialized & disjoint):
    //   [ 0,16M) hs_bf : hidden bf16; later attn-out bf16
    //   [16,24M) wbuf  : weights bf16 (Q 8M; then KV 4M; then O 8M)
    //   [24,56M) gout  : fp32 GEMM out (Q all 32M; KV uses [24,40) only)
    //   [40,44M) Kr    : bf16 [b][4][s][128]
    //   [44,48M) Vt    : bf16 [b][4][d][s] transposed
    //   [56,72M) Qr    : bf16 [b][16][s][128]
    char* ws = (char*)d_ws;
    u16* hs_bf  = (u16*)(ws);
    u16* wbuf   = (u16*)(ws + (16ul << 20));
    float* gout = (float*)(ws + (24ul << 20));
    u16* Kr     = (u16*)(ws + (40ul << 20));
    u16* Vt     = (u16*)(ws + (44ul << 20));
    u16* Qr     = (u16*)(ws + (56ul << 20));
    (void)ws_size; (void)in_sizes; (void)n_in; (void)out_size;

    // hidden -> bf16
    conv_f32_bf16<<<(MROWS * HID / 4 + 255) / 256, 256, 0, stream>>>(hs, hs_bf, MROWS * HID / 4);

    // Q = hs @ q_w^T ; rmsnorm + rope
    conv_f32_bf16<<<(HID * HID / 4 + 255) / 256, 256, 0, stream>>>(q_w, wbuf, HID * HID / 4);
    dim3 gq(MROWS / 128, HID / 128);
    gemm_bt<<<gq, 256, 0, stream>>>(hs_bf, wbuf, gout, MROWS, HID, HID);
    rope_norm<<<MROWS, 256, 0, stream>>>(gout, Qr, qnw, NH, HID, 0);

    // K|V fused projection: wbuf rows [0,512)=k_w, [512,1024)=v_w; N=1024
    conv_f32_bf16<<<(NKV * HD * HID / 4 + 255) / 256, 256, 0, stream>>>(k_w, wbuf, NKV * HD * HID / 4);
    conv_f32_bf16<<<(NKV * HD * HID / 4 + 255) / 256, 256, 0, stream>>>(v_w, wbuf + NKV * HD * HID, NKV * HD * HID / 4);
    dim3 gkv(MROWS / 128, (2 * NKV * HD) / 128);
    gemm_bt<<<gkv, 256, 0, stream>>>(hs_bf, wbuf, gout, MROWS, 2 * NKV * HD, HID);
    rope_norm<<<MROWS, 256, 0, stream>>>(gout, Kr, knw, NKV, 2 * NKV * HD, 0);
    pack_vt<<<BATCH * NKV * (S_LEN / 64), 256, 0, stream>>>(gout, Vt, 2 * NKV * HD, NKV * HD);

    // attention -> hs_bf  (grid = 8 slots x 32 bh x 4 groups = 1024, 128 thr)
    flash_attn<<<1024, 128, 0, stream>>>(Qr, Kr, Vt, hs_bf);

    // out = attn @ o_w^T
    conv_f32_bf16<<<(HID * HID / 4 + 255) / 256, 256, 0, stream>>>(o_w, wbuf, HID * HID / 4);
    gemm_bt<<<gq, 256, 0, stream>>>(hs_bf, wbuf, out, MROWS, HID, HID);
}

// Round 3
// 489.706 us; speedup vs baseline: 1.1960x; 1.0331x over previous
//
#include <hip/hip_runtime.h>
#include <stdint.h>

#define S_LEN 2048
#define BATCH 2
#define NH 16
#define NKV 4
#define HD 128
#define HID 2048
#define MROWS (BATCH * S_LEN)  // 4096
#define KST 144                // K-tile LDS row stride (u16): 288B, 16B-aligned, 4-way bank max

typedef unsigned short u16;
typedef __attribute__((ext_vector_type(8))) short frag_ab;
typedef __attribute__((ext_vector_type(4))) float frag_cd;

static __device__ __forceinline__ float bf2f(u16 v) {
    union { unsigned u; float f; } t; t.u = ((unsigned)v) << 16; return t.f;
}
static __device__ __forceinline__ u16 f2bf(float f) {
    union { float f; unsigned u; } t; t.f = f;
    unsigned r = t.u + 0x7fffu + ((t.u >> 16) & 1u);  // RNE
    return (u16)(r >> 16);
}
// async global->LDS, 16B per lane; LDS dest = wave-uniform base + lane*16
static __device__ __forceinline__ void load_lds16(const u16* g, u16* l) {
    __builtin_amdgcn_global_load_lds((const __attribute__((address_space(1))) void*)g,
                                     (__attribute__((address_space(3))) void*)l, 16, 0, 0);
}

// ---------------- fp32 -> bf16 bulk convert ----------------
__global__ __launch_bounds__(256) void conv_f32_bf16(const float* __restrict__ src,
                                                     u16* __restrict__ dst, int n4) {
    int i = blockIdx.x * 256 + threadIdx.x;
    if (i >= n4) return;
    float4 v = ((const float4*)src)[i];
    ushort4 o;
    o.x = f2bf(v.x); o.y = f2bf(v.y); o.z = f2bf(v.z); o.w = f2bf(v.w);
    ((ushort4*)dst)[i] = o;
}

// ---------------- C = A (MxK) * B^T (B stored [N][K]), fp32 out ----------------
// 128x128 tile, 4 waves x (4x4) 16x16x32 MFMA, BK=32, global_load_lds width=16
// staging (m97 ladder step 3).
__global__ __launch_bounds__(256) void gemm_bt(const u16* __restrict__ A, const u16* __restrict__ B,
                                               float* __restrict__ C, int M, int N, int K) {
    __shared__ u16 As[128 * 32];
    __shared__ u16 Bs[128 * 32];
    const int tid = threadIdx.x;
    const int wave = tid >> 6, lane = tid & 63;
    const int quad = lane >> 4, lr = lane & 15;
    const int wm = (wave & 1) * 64, wn = (wave >> 1) * 64;
    const long bm = (long)blockIdx.x * 128, bn = (long)blockIdx.y * 128;
    // staging: chunk c = issue*256 + wave*64 + lane; row=c>>2, col16=c&3
    const int srow = (wave << 4) + (lane >> 2);   // + issue*64
    const int scol = (lane & 3) * 8;
    const u16* Ag = A + (bm + srow) * (long)K + scol;
    const u16* Bg = B + (bn + srow) * (long)K + scol;
    u16* AsW = As + wave * 512;                    // + issue*2048 (u16)
    u16* BsW = Bs + wave * 512;

    frag_cd acc[4][4];
#pragma unroll
    for (int i = 0; i < 4; i++)
#pragma unroll
        for (int j = 0; j < 4; j++) acc[i][j] = (frag_cd){0.f, 0.f, 0.f, 0.f};

    for (int k0 = 0; k0 < K; k0 += 32) {
        __syncthreads();  // prev iter's LDS readers done
        load_lds16(Ag + k0, AsW);
        load_lds16(Ag + (long)64 * K + k0, AsW + 2048);
        load_lds16(Bg + k0, BsW);
        load_lds16(Bg + (long)64 * K + k0, BsW + 2048);
        __syncthreads();  // staging complete (vmcnt(0) drained by barrier)
        frag_ab af[4], bfr[4];
#pragma unroll
        for (int i = 0; i < 4; i++) af[i] = *(const frag_ab*)(As + (wm + i * 16 + lr) * 32 + quad * 8);
#pragma unroll
        for (int j = 0; j < 4; j++) bfr[j] = *(const frag_ab*)(Bs + (wn + j * 16 + lr) * 32 + quad * 8);
#pragma unroll
        for (int i = 0; i < 4; i++)
#pragma unroll
            for (int j = 0; j < 4; j++)
                acc[i][j] = __builtin_amdgcn_mfma_f32_16x16x32_bf16(af[i], bfr[j], acc[i][j], 0, 0, 0);
    }
    // C/D layout: col = lane&15, row = (lane>>4)*4 + reg   [measured m89/m91]
#pragma unroll
    for (int i = 0; i < 4; i++)
#pragma unroll
        for (int j = 0; j < 4; j++)
#pragma unroll
            for (int r = 0; r < 4; r++) {
                long row = bm + wm + i * 16 + quad * 4 + r;
                long col = bn + wn + j * 16 + lr;
                C[row * N + col] = acc[i][j][r];
            }
}

// ---------------- RMSNorm(head_dim) + RoPE, fp32 in -> bf16 out [b][h][s][d] ----------------
__global__ __launch_bounds__(256) void rope_norm(const float* __restrict__ src, u16* __restrict__ dst,
                                                 const float* __restrict__ nw, int nh, int stride, int coff) {
    const int m = blockIdx.x;                 // 0..4095 (b*S+s)
    const int wave = threadIdx.x >> 6, lane = threadIdx.x & 63;
    const int s = m & (S_LEN - 1), b = m >> 11;
    const int d0 = 2 * lane;
    const float w0 = nw[d0], w1 = nw[d0 + 1];
    const int i0 = d0 & 63;
    const float lnt_over = 13.122363377404328f / 64.f;  // ln(500000)/64
    float inv0 = expf(-(float)i0 * lnt_over);
    float inv1 = expf(-(float)(i0 + 1) * lnt_over);
    float c0 = cosf((float)s * inv0), sn0 = sinf((float)s * inv0);
    float c1 = cosf((float)s * inv1), sn1 = sinf((float)s * inv1);
    for (int h = wave; h < nh; h += 4) {
        float2 x = *(const float2*)(src + (long)m * stride + coff + h * HD + d0);
        float ss = x.x * x.x + x.y * x.y;
#pragma unroll
        for (int off = 1; off < 64; off <<= 1) ss += __shfl_xor(ss, off);
        float rs = rsqrtf(ss * (1.f / HD) + 1e-5f);
        float xn0 = x.x * rs * w0;
        float xn1 = x.y * rs * w1;
        float p0 = __shfl_xor(xn0, 32);
        float p1 = __shfl_xor(xn1, 32);
        float r0 = (lane < 32) ? -p0 : p0;   // rotate_half
        float r1 = (lane < 32) ? -p1 : p1;
        float y0 = xn0 * c0 + r0 * sn0;
        float y1 = xn1 * c1 + r1 * sn1;
        unsigned outw = (unsigned)f2bf(y0) | ((unsigned)f2bf(y1) << 16);
        *(unsigned*)(dst + (((long)(b * nh + h) * S_LEN + s) * HD + d0)) = outw;
    }
}

// ---------------- V: fp32 gout [m][coff+kh*128+d] -> bf16 TRANSPOSED [b][kh][d][s] ----------------
__global__ __launch_bounds__(256) void pack_vt(const float* __restrict__ src, u16* __restrict__ dst,
                                               int stride, int coff) {
    __shared__ u16 t[128 * 72];  // [d][s], rows padded 64->72
    const int tid = threadIdx.x;
    const int st = blockIdx.x & 31;
    const int kh = (blockIdx.x >> 5) & 3;
    const int b = blockIdx.x >> 7;
    const long m0 = (long)b * S_LEN + st * 64;
#pragma unroll
    for (int c = 0; c < 8; c++) {
        int idx = c * 256 + tid;           // 0..2047 float4s
        int r = idx >> 5, cg = idx & 31;   // s-row 0..63, col-group 0..31
        float4 v = *(const float4*)(src + (m0 + r) * stride + coff + kh * HD + cg * 4);
        int col = cg * 4;
        t[(col + 0) * 72 + r] = f2bf(v.x);
        t[(col + 1) * 72 + r] = f2bf(v.y);
        t[(col + 2) * 72 + r] = f2bf(v.z);
        t[(col + 3) * 72 + r] = f2bf(v.w);
    }
    __syncthreads();
    const int d = tid >> 1, sh = (tid & 1) * 32;
    u16* dp = dst + ((long)(b * NKV + kh) * HD + d) * S_LEN + st * 64 + sh;
    const u16* tp = &t[d * 72 + sh];
    *(uint4*)(dp + 0)  = *(const uint4*)(tp + 0);
    *(uint4*)(dp + 8)  = *(const uint4*)(tp + 8);
    *(uint4*)(dp + 16) = *(const uint4*)(tp + 16);
    *(uint4*)(dp + 24) = *(const uint4*)(tp + 24);
}

// ---------------- MFMA flash attention v6 ----------------
// v3 decomposition (4-wave 256-thr blocks, 128-row causal-paired Q-tiles,
// uniform 34 kt, grid 256 — guaranteed balance) + latency-chain surgery:
//  * K-tile double-buffered in LDS (reg-staged, 4 waves cooperative): global
//    loads for tile kt+1 issue at the TOP of kt's body, ds_write at the
//    bottom -> K latency hides under the whole kt body (QK+softmax+PV).
//    Row stride KST=144 u16 (288B): ds_read_b128 fragment reads are 4-way
//    bank conflict (1.58x) vs 32-way at a 256B stride.
//  * V fragment loads hoisted BEFORE softmax -> V latency hides under ~2K
//    cycles of softmax/Pls VALU work.
// Numerics identical to v3/v5 (same bytes, same order).
__global__ __launch_bounds__(256) void flash_attn(const u16* __restrict__ Q, const u16* __restrict__ K,
                                                  const u16* __restrict__ Vt, u16* __restrict__ O) {
    __shared__ u16 Ks[2][64 * KST];   // 2 x 18432 B
    __shared__ u16 Pls[4 * 32 * 80];  // 20480 B  (total 57344 <= 64K)
    const int tid = threadIdx.x;
    const int wave = tid >> 6, lane = tid & 63;
    const int quad = lane >> 4, lr = lane & 15;
    const int p = blockIdx.x & 7;
    const int h = (blockIdx.x >> 3) & 15;
    const int b = blockIdx.x >> 7;
    const int kh = h >> 2;
    const float scale = 0.08838834764831845f;  // 1/sqrt(128)
    const u16* Qb = Q + ((long)(b * NH + h) * S_LEN) * HD;
    const u16* Kb = K + ((long)(b * NKV + kh) * S_LEN) * HD;
    const u16* Vb = Vt + ((long)(b * NKV + kh) * HD) * S_LEN;
    const int pbase = wave * 32 * 80;
    // staging: chunk cc*256+tid -> K-tile row cc*16+(tid>>4), 16B col (tid&15)
    const int strow = tid >> 4;
    const int stcol = (tid & 15) * 8;  // u16 offset

    for (int ph = 0; ph < 2; ph++) {
        const int t = ph ? p : (15 - p);   // heavy tile first
        const int q0 = t * 128;
        frag_ab qf[2][4];
#pragma unroll
        for (int mt = 0; mt < 2; mt++) {
            int qrow = q0 + wave * 32 + mt * 16 + lr;
#pragma unroll
            for (int ks = 0; ks < 4; ks++)
                qf[mt][ks] = *(const frag_ab*)(Qb + (long)qrow * HD + ks * 32 + quad * 8);
        }
        frag_cd oa[2][8];
        float m_i[2][4], l_i[2][4];
#pragma unroll
        for (int mt = 0; mt < 2; mt++) {
#pragma unroll
            for (int dt = 0; dt < 8; dt++) oa[mt][dt] = (frag_cd){0.f, 0.f, 0.f, 0.f};
#pragma unroll
            for (int r = 0; r < 4; r++) { m_i[mt][r] = -3e38f; l_i[mt][r] = 0.f; }
        }
        const int nkt = 2 * t + 2;

        // prologue: stage K tile 0 into buf 0 (prev phase's readers drained by
        // its last loop-end barrier; ph0 has no prior readers)
        uint4 sreg[4];
#pragma unroll
        for (int cc = 0; cc < 4; cc++)
            sreg[cc] = *(const uint4*)(Kb + (long)(cc * 16 + strow) * HD + stcol);
#pragma unroll
        for (int cc = 0; cc < 4; cc++)
            *(uint4*)(&Ks[0][(cc * 16 + strow) * KST + stcol]) = sreg[cc];
        __syncthreads();
        int cur = 0;

        for (int kt = 0; kt < nkt; kt++) {
            const int j0 = kt * 64;
            // issue next K-tile's global loads FIRST (latency spans whole body)
            if (kt + 1 < nkt) {
#pragma unroll
                for (int cc = 0; cc < 4; cc++)
                    sreg[cc] = *(const uint4*)(Kb + (long)(j0 + 64 + cc * 16 + strow) * HD + stcol);
            }
            // S = Q K^T  (kf from LDS buf cur)
            frag_cd sa[2][4];
#pragma unroll
            for (int mt = 0; mt < 2; mt++)
#pragma unroll
                for (int nt = 0; nt < 4; nt++) sa[mt][nt] = (frag_cd){0.f, 0.f, 0.f, 0.f};
#pragma unroll
            for (int nt = 0; nt < 4; nt++) {
                frag_ab kf[4];
#pragma unroll
                for (int ks = 0; ks < 4; ks++)
                    kf[ks] = *(const frag_ab*)(&Ks[cur][(nt * 16 + lr) * KST + ks * 32 + quad * 8]);
#pragma unroll
                for (int mt = 0; mt < 2; mt++)
#pragma unroll
                    for (int ks = 0; ks < 4; ks++)
                        sa[mt][nt] = __builtin_amdgcn_mfma_f32_16x16x32_bf16(qf[mt][ks], kf[ks], sa[mt][nt], 0, 0, 0);
            }
            // early V fragment loads (hide under softmax)
            frag_ab vf[2][8];
#pragma unroll
            for (int ks = 0; ks < 2; ks++)
#pragma unroll
                for (int dt = 0; dt < 8; dt++)
                    vf[ks][dt] = *(const frag_ab*)(Vb + (long)(dt * 16 + lr) * S_LEN + j0 + ks * 32 + quad * 8);

            const bool need_mask = (j0 + 63) > (q0 + wave * 32);
            // online softmax (C-layout: row=quad*4+r, col=lr)
#pragma unroll
            for (int mt = 0; mt < 2; mt++) {
                float mrow[4] = {-3e38f, -3e38f, -3e38f, -3e38f};
#pragma unroll
                for (int nt = 0; nt < 4; nt++) {
                    int key = j0 + nt * 16 + lr;
#pragma unroll
                    for (int r = 0; r < 4; r++) {
                        int qrow = q0 + wave * 32 + mt * 16 + quad * 4 + r;
                        float v = sa[mt][nt][r] * scale;
                        if (need_mask) v = (key <= qrow) ? v : -3e38f;
                        sa[mt][nt][r] = v;
                        mrow[r] = fmaxf(mrow[r], v);
                    }
                }
#pragma unroll
                for (int off = 1; off < 16; off <<= 1)
#pragma unroll
                    for (int r = 0; r < 4; r++) mrow[r] = fmaxf(mrow[r], __shfl_xor(mrow[r], off));
                float rs[4];
#pragma unroll
                for (int r = 0; r < 4; r++) {
                    float mn = fmaxf(m_i[mt][r], mrow[r]);
                    float alpha = __expf(m_i[mt][r] - mn);
                    m_i[mt][r] = mn;
                    l_i[mt][r] *= alpha;
                    rs[r] = 0.f;
#pragma unroll
                    for (int dt = 0; dt < 8; dt++) oa[mt][dt][r] *= alpha;
                }
#pragma unroll
                for (int nt = 0; nt < 4; nt++)
#pragma unroll
                    for (int r = 0; r < 4; r++) {
                        float pw = __expf(sa[mt][nt][r] - m_i[mt][r]);
                        rs[r] += pw;
                        Pls[pbase + (mt * 16 + quad * 4 + r) * 80 + nt * 16 + lr] = f2bf(pw);
                    }
#pragma unroll
                for (int off = 1; off < 16; off <<= 1)
#pragma unroll
                    for (int r = 0; r < 4; r++) rs[r] += __shfl_xor(rs[r], off);
#pragma unroll
                for (int r = 0; r < 4; r++) l_i[mt][r] += rs[r];
            }

            // O += P V  (pf via per-wave LDS; vf pre-loaded)
#pragma unroll
            for (int ks = 0; ks < 2; ks++) {
                frag_ab pf[2];
#pragma unroll
                for (int mt = 0; mt < 2; mt++)
                    pf[mt] = *(const frag_ab*)&Pls[pbase + (mt * 16 + lr) * 80 + ks * 32 + quad * 8];
#pragma unroll
                for (int dt = 0; dt < 8; dt++) {
                    oa[0][dt] = __builtin_amdgcn_mfma_f32_16x16x32_bf16(pf[0], vf[ks][dt], oa[0][dt], 0, 0, 0);
                    oa[1][dt] = __builtin_amdgcn_mfma_f32_16x16x32_bf16(pf[1], vf[ks][dt], oa[1][dt], 0, 0, 0);
                }
            }
            // write staged K tile to the other buffer; barrier flips it live
            if (kt + 1 < nkt) {
#pragma unroll
                for (int cc = 0; cc < 4; cc++)
                    *(uint4*)(&Ks[cur ^ 1][(cc * 16 + strow) * KST + stcol]) = sreg[cc];
            }
            __syncthreads();
            cur ^= 1;
        }

        // epilogue: O[b*S+s][h*128+d] bf16
#pragma unroll
        for (int mt = 0; mt < 2; mt++) {
            float inv[4];
#pragma unroll
            for (int r = 0; r < 4; r++) inv[r] = 1.f / l_i[mt][r];
#pragma unroll
            for (int dt = 0; dt < 8; dt++)
#pragma unroll
                for (int r = 0; r < 4; r++) {
                    int s = q0 + wave * 32 + mt * 16 + quad * 4 + r;
                    O[((long)b * S_LEN + s) * (NH * HD) + h * HD + dt * 16 + lr] =
                        f2bf(oa[mt][dt][r] * inv[r]);
                }
        }
    }
}

extern "C" void kernel_launch(void* const* d_in, const int* in_sizes, int n_in,
                              void* d_out, int out_size, void* d_ws, size_t ws_size,
                              hipStream_t stream) {
    const float* hs  = (const float*)d_in[0];
    const float* q_w = (const float*)d_in[1];
    const float* k_w = (const float*)d_in[2];
    const float* v_w = (const float*)d_in[3];
    const float* o_w = (const float*)d_in[4];
    const float* qnw = (const float*)d_in[5];
    const float* knw = (const float*)d_in[6];
    float* out = (float*)d_out;

    // Workspace (72 MiB, live ranges stream-serialized & disjoint):
    //   [ 0,16M) hs_bf : hidden bf16; later attn-out bf16
    //   [16,24M) wbuf  : weights bf16 (Q 8M; then KV 4M; then O 8M)
    //   [24,56M) gout  : fp32 GEMM out (Q all 32M; KV uses [24,40) only)
    //   [40,44M) Kr    : bf16 [b][4][s][128]
    //   [44,48M) Vt    : bf16 [b][4][d][s] transposed
    //   [56,72M) Qr    : bf16 [b][16][s][128]
    char* ws = (char*)d_ws;
    u16* hs_bf  = (u16*)(ws);
    u16* wbuf   = (u16*)(ws + (16ul << 20));
    float* gout = (float*)(ws + (24ul << 20));
    u16* Kr     = (u16*)(ws + (40ul << 20));
    u16* Vt     = (u16*)(ws + (44ul << 20));
    u16* Qr     = (u16*)(ws + (56ul << 20));
    (void)ws_size; (void)in_sizes; (void)n_in; (void)out_size;

    // hidden -> bf16
    conv_f32_bf16<<<(MROWS * HID / 4 + 255) / 256, 256, 0, stream>>>(hs, hs_bf, MROWS * HID / 4);

    // Q = hs @ q_w^T ; rmsnorm + rope
    conv_f32_bf16<<<(HID * HID / 4 + 255) / 256, 256, 0, stream>>>(q_w, wbuf, HID * HID / 4);
    dim3 gq(MROWS / 128, HID / 128);
    gemm_bt<<<gq, 256, 0, stream>>>(hs_bf, wbuf, gout, MROWS, HID, HID);
    rope_norm<<<MROWS, 256, 0, stream>>>(gout, Qr, qnw, NH, HID, 0);

    // K|V fused projection: wbuf rows [0,512)=k_w, [512,1024)=v_w; N=1024
    conv_f32_bf16<<<(NKV * HD * HID / 4 + 255) / 256, 256, 0, stream>>>(k_w, wbuf, NKV * HD * HID / 4);
    conv_f32_bf16<<<(NKV * HD * HID / 4 + 255) / 256, 256, 0, stream>>>(v_w, wbuf + NKV * HD * HID, NKV * HD * HID / 4);
    dim3 gkv(MROWS / 128, (2 * NKV * HD) / 128);
    gemm_bt<<<gkv, 256, 0, stream>>>(hs_bf, wbuf, gout, MROWS, 2 * NKV * HD, HID);
    rope_norm<<<MROWS, 256, 0, stream>>>(gout, Kr, knw, NKV, 2 * NKV * HD, 0);
    pack_vt<<<BATCH * NKV * (S_LEN / 64), 256, 0, stream>>>(gout, Vt, 2 * NKV * HD, NKV * HD);

    // attention -> hs_bf  (grid = 8 pairs x 16 h x 2 b = 256, 4-wave blocks)
    flash_attn<<<8 * NH * BATCH, 256, 0, stream>>>(Qr, Kr, Vt, hs_bf);

    // out = attn @ o_w^T
    conv_f32_bf16<<<(HID * HID / 4 + 255) / 256, 256, 0, stream>>>(o_w, wbuf, HID * HID / 4);
    gemm_bt<<<gq, 256, 0, stream>>>(hs_bf, wbuf, out, MROWS, HID, HID);
}

// Round 5
// 445.884 us; speedup vs baseline: 1.3136x; 1.0983x over previous
//
#include <hip/hip_runtime.h>
#include <stdint.h>

#define S_LEN 2048
#define BATCH 2
#define NH 16
#define NKV 4
#define HD 128
#define HID 2048
#define MROWS (BATCH * S_LEN)  // 4096

typedef unsigned short u16;
typedef __attribute__((ext_vector_type(8))) short frag_ab;
typedef __attribute__((ext_vector_type(4))) float frag_cd;

static __device__ __forceinline__ float bf2f(u16 v) {
    union { unsigned u; float f; } t; t.u = ((unsigned)v) << 16; return t.f;
}
static __device__ __forceinline__ u16 f2bf(float f) {
    union { float f; unsigned u; } t; t.f = f;
    unsigned r = t.u + 0x7fffu + ((t.u >> 16) & 1u);  // RNE
    return (u16)(r >> 16);
}
// async global->LDS, 16B per lane; LDS dest = wave-uniform base + lane*16
static __device__ __forceinline__ void load_lds16(const u16* g, u16* l) {
    __builtin_amdgcn_global_load_lds((const __attribute__((address_space(1))) void*)g,
                                     (__attribute__((address_space(3))) void*)l, 16, 0, 0);
}

// ---------------- fp32 -> bf16 bulk convert ----------------
__global__ __launch_bounds__(256) void conv_f32_bf16(const float* __restrict__ src,
                                                     u16* __restrict__ dst, int n4) {
    int i = blockIdx.x * 256 + threadIdx.x;
    if (i >= n4) return;
    float4 v = ((const float4*)src)[i];
    ushort4 o;
    o.x = f2bf(v.x); o.y = f2bf(v.y); o.z = f2bf(v.z); o.w = f2bf(v.w);
    ((ushort4*)dst)[i] = o;
}

// ---------------- C = A (MxK) * B^T (B stored [N][K]), fp32 out ----------------
// 128x128 tile, 4 waves x (4x4) 16x16x32 MFMA, BK=32, global_load_lds width=16
// staging (m97 ladder step 3).
__global__ __launch_bounds__(256) void gemm_bt(const u16* __restrict__ A, const u16* __restrict__ B,
                                               float* __restrict__ C, int M, int N, int K) {
    __shared__ u16 As[128 * 32];
    __shared__ u16 Bs[128 * 32];
    const int tid = threadIdx.x;
    const int wave = tid >> 6, lane = tid & 63;
    const int quad = lane >> 4, lr = lane & 15;
    const int wm = (wave & 1) * 64, wn = (wave >> 1) * 64;
    const long bm = (long)blockIdx.x * 128, bn = (long)blockIdx.y * 128;
    // staging: chunk c = issue*256 + wave*64 + lane; row=c>>2, col16=c&3
    const int srow = (wave << 4) + (lane >> 2);   // + issue*64
    const int scol = (lane & 3) * 8;
    const u16* Ag = A + (bm + srow) * (long)K + scol;
    const u16* Bg = B + (bn + srow) * (long)K + scol;
    u16* AsW = As + wave * 512;                    // + issue*2048 (u16)
    u16* BsW = Bs + wave * 512;

    frag_cd acc[4][4];
#pragma unroll
    for (int i = 0; i < 4; i++)
#pragma unroll
        for (int j = 0; j < 4; j++) acc[i][j] = (frag_cd){0.f, 0.f, 0.f, 0.f};

    for (int k0 = 0; k0 < K; k0 += 32) {
        __syncthreads();  // prev iter's LDS readers done
        load_lds16(Ag + k0, AsW);
        load_lds16(Ag + (long)64 * K + k0, AsW + 2048);
        load_lds16(Bg + k0, BsW);
        load_lds16(Bg + (long)64 * K + k0, BsW + 2048);
        __syncthreads();  // staging complete (vmcnt(0) drained by barrier)
        frag_ab af[4], bfr[4];
#pragma unroll
        for (int i = 0; i < 4; i++) af[i] = *(const frag_ab*)(As + (wm + i * 16 + lr) * 32 + quad * 8);
#pragma unroll
        for (int j = 0; j < 4; j++) bfr[j] = *(const frag_ab*)(Bs + (wn + j * 16 + lr) * 32 + quad * 8);
#pragma unroll
        for (int i = 0; i < 4; i++)
#pragma unroll
            for (int j = 0; j < 4; j++)
                acc[i][j] = __builtin_amdgcn_mfma_f32_16x16x32_bf16(af[i], bfr[j], acc[i][j], 0, 0, 0);
    }
    // C/D layout: col = lane&15, row = (lane>>4)*4 + reg   [measured m89/m91]
#pragma unroll
    for (int i = 0; i < 4; i++)
#pragma unroll
        for (int j = 0; j < 4; j++)
#pragma unroll
            for (int r = 0; r < 4; r++) {
                long row = bm + wm + i * 16 + quad * 4 + r;
                long col = bn + wn + j * 16 + lr;
                C[row * N + col] = acc[i][j][r];
            }
}

// ---------------- RMSNorm(head_dim) + RoPE, fp32 in -> bf16 out [b][h][s][d] ----------------
__global__ __launch_bounds__(256) void rope_norm(const float* __restrict__ src, u16* __restrict__ dst,
                                                 const float* __restrict__ nw, int nh, int stride, int coff) {
    const int m = blockIdx.x;                 // 0..4095 (b*S+s)
    const int wave = threadIdx.x >> 6, lane = threadIdx.x & 63;
    const int s = m & (S_LEN - 1), b = m >> 11;
    const int d0 = 2 * lane;
    const float w0 = nw[d0], w1 = nw[d0 + 1];
    const int i0 = d0 & 63;
    const float lnt_over = 13.122363377404328f / 64.f;  // ln(500000)/64
    float inv0 = expf(-(float)i0 * lnt_over);
    float inv1 = expf(-(float)(i0 + 1) * lnt_over);
    float c0 = cosf((float)s * inv0), sn0 = sinf((float)s * inv0);
    float c1 = cosf((float)s * inv1), sn1 = sinf((float)s * inv1);
    for (int h = wave; h < nh; h += 4) {
        float2 x = *(const float2*)(src + (long)m * stride + coff + h * HD + d0);
        float ss = x.x * x.x + x.y * x.y;
#pragma unroll
        for (int off = 1; off < 64; off <<= 1) ss += __shfl_xor(ss, off);
        float rs = rsqrtf(ss * (1.f / HD) + 1e-5f);
        float xn0 = x.x * rs * w0;
        float xn1 = x.y * rs * w1;
        float p0 = __shfl_xor(xn0, 32);
        float p1 = __shfl_xor(xn1, 32);
        float r0 = (lane < 32) ? -p0 : p0;   // rotate_half
        float r1 = (lane < 32) ? -p1 : p1;
        float y0 = xn0 * c0 + r0 * sn0;
        float y1 = xn1 * c1 + r1 * sn1;
        unsigned outw = (unsigned)f2bf(y0) | ((unsigned)f2bf(y1) << 16);
        *(unsigned*)(dst + (((long)(b * nh + h) * S_LEN + s) * HD + d0)) = outw;
    }
}

// ---------------- V: fp32 gout [m][coff+kh*128+d] -> bf16 TRANSPOSED [b][kh][d][s] ----------------
__global__ __launch_bounds__(256) void pack_vt(const float* __restrict__ src, u16* __restrict__ dst,
                                               int stride, int coff) {
    __shared__ u16 t[128 * 72];  // [d][s], rows padded 64->72
    const int tid = threadIdx.x;
    const int st = blockIdx.x & 31;
    const int kh = (blockIdx.x >> 5) & 3;
    const int b = blockIdx.x >> 7;
    const long m0 = (long)b * S_LEN + st * 64;
#pragma unroll
    for (int c = 0; c < 8; c++) {
        int idx = c * 256 + tid;           // 0..2047 float4s
        int r = idx >> 5, cg = idx & 31;   // s-row 0..63, col-group 0..31
        float4 v = *(const float4*)(src + (m0 + r) * stride + coff + kh * HD + cg * 4);
        int col = cg * 4;
        t[(col + 0) * 72 + r] = f2bf(v.x);
        t[(col + 1) * 72 + r] = f2bf(v.y);
        t[(col + 2) * 72 + r] = f2bf(v.z);
        t[(col + 3) * 72 + r] = f2bf(v.w);
    }
    __syncthreads();
    const int d = tid >> 1, sh = (tid & 1) * 32;
    u16* dp = dst + ((long)(b * NKV + kh) * HD + d) * S_LEN + st * 64 + sh;
    const u16* tp = &t[d * 72 + sh];
    *(uint4*)(dp + 0)  = *(const uint4*)(tp + 0);
    *(uint4*)(dp + 8)  = *(const uint4*)(tp + 8);
    *(uint4*)(dp + 16) = *(const uint4*)(tp + 16);
    *(uint4*)(dp + 24) = *(const uint4*)(tp + 24);
}

// ---------------- MFMA flash attention v7: split-K flash-decoding ----------------
// Block = 4 waves, ONE 32-row Q-tile; waves split the key range strided
// (wave w: kt = w, w+4, ...). Per-wave inner body identical to verified v5
// (32 rows via mt=2, K/V direct from global, vf hoisted before softmax, no
// barriers in kt loop). Grid = 64 tiles x 32 bh = 2048 blocks, heavy-first
// (t = 63-tt); (b,kh) in low 3 bits -> each XCD's round-robin share has one
// KV working set (1MB KV + 2MB Q < 4MB L2). ~180 VGPR -> 2 waves/SIMD ->
// 2 blocks/CU resident, 4x oversubscribed -> refill absorbs causal imbalance.
// End-of-block flash-decoding merge: publish (m,l), rescale in-reg, serialized
// float4 accumulate into 16KB LDS, cooperative epilogue.
__global__ __launch_bounds__(256, 2) void flash_attn(const u16* __restrict__ Q, const u16* __restrict__ K,
                                                     const u16* __restrict__ Vt, u16* __restrict__ O) {
    __shared__ u16 Pls[4 * 32 * 80];        // 20480 B (per-wave P C->A round-trip)
    __shared__ float macc[2][8][16][16];    // 16384 B [mt][dt][col][row]
    __shared__ float mlb[4][2][16][2];      // 1024 B  [wave][mt][row][{m,l}]
    const int tid = threadIdx.x;
    const int wave = tid >> 6, lane = tid & 63;
    const int quad = lane >> 4, lr = lane & 15;
    const int g = blockIdx.x & 7;           // (b,kh) group -> XCD locality
    const int sub = (blockIdx.x >> 3) & 3;  // h within kv group
    const int tt = blockIdx.x >> 5;         // 0..63
    const int t = 63 - tt;                  // heavy tiles dispatched first
    const int b = g >> 2, kh = g & 3;
    const int h = kh * 4 + sub;
    const float scale = 0.08838834764831845f;  // 1/sqrt(128)
    const u16* Qb = Q + ((long)(b * NH + h) * S_LEN) * HD;
    const u16* Kb = K + ((long)(b * NKV + kh) * S_LEN) * HD;
    const u16* Vb = Vt + ((long)(b * NKV + kh) * HD) * S_LEN;
    const int pbase = wave * 32 * 80;

    const int q0 = t * 32;
    const int nkt = (t >> 1) + 1;           // key tiles of 64 covering [0, 32t+32)

    frag_ab qf[2][4];
#pragma unroll
    for (int mt = 0; mt < 2; mt++) {
        int qrow = q0 + mt * 16 + lr;
#pragma unroll
        for (int ks = 0; ks < 4; ks++)
            qf[mt][ks] = *(const frag_ab*)(Qb + (long)qrow * HD + ks * 32 + quad * 8);
    }
    frag_cd oa[2][8];
    float m_i[2][4], l_i[2][4];
#pragma unroll
    for (int mt = 0; mt < 2; mt++) {
#pragma unroll
        for (int dt = 0; dt < 8; dt++) oa[mt][dt] = (frag_cd){0.f, 0.f, 0.f, 0.f};
#pragma unroll
        for (int r = 0; r < 4; r++) { m_i[mt][r] = -3e38f; l_i[mt][r] = 0.f; }
    }

    for (int kt = wave; kt < nkt; kt += 4) {
        const int j0 = kt * 64;
        // S = Q K^T  (kf direct from global K[key][d])
        frag_cd sa[2][4];
#pragma unroll
        for (int mt = 0; mt < 2; mt++)
#pragma unroll
            for (int nt = 0; nt < 4; nt++) sa[mt][nt] = (frag_cd){0.f, 0.f, 0.f, 0.f};
#pragma unroll
        for (int nt = 0; nt < 4; nt++) {
            frag_ab kf[4];
#pragma unroll
            for (int ks = 0; ks < 4; ks++)
                kf[ks] = *(const frag_ab*)(Kb + (long)(j0 + nt * 16 + lr) * HD + ks * 32 + quad * 8);
#pragma unroll
            for (int mt = 0; mt < 2; mt++)
#pragma unroll
                for (int ks = 0; ks < 4; ks++)
                    sa[mt][nt] = __builtin_amdgcn_mfma_f32_16x16x32_bf16(qf[mt][ks], kf[ks], sa[mt][nt], 0, 0, 0);
        }
        // early V fragment loads (hide latency under softmax)
        frag_ab vf[2][8];
#pragma unroll
        for (int ks = 0; ks < 2; ks++)
#pragma unroll
            for (int dt = 0; dt < 8; dt++)
                vf[ks][dt] = *(const frag_ab*)(Vb + (long)(dt * 16 + lr) * S_LEN + j0 + ks * 32 + quad * 8);

        const bool need_mask = (j0 + 63) > q0;
        // online softmax (C-layout: row=quad*4+r, col=lr)
#pragma unroll
        for (int mt = 0; mt < 2; mt++) {
            float mrow[4] = {-3e38f, -3e38f, -3e38f, -3e38f};
#pragma unroll
            for (int nt = 0; nt < 4; nt++) {
                int key = j0 + nt * 16 + lr;
#pragma unroll
                for (int r = 0; r < 4; r++) {
                    int qrow = q0 + mt * 16 + quad * 4 + r;
                    float v = sa[mt][nt][r] * scale;
                    if (need_mask) v = (key <= qrow) ? v : -3e38f;
                    sa[mt][nt][r] = v;
                    mrow[r] = fmaxf(mrow[r], v);
                }
            }
#pragma unroll
            for (int off = 1; off < 16; off <<= 1)
#pragma unroll
                for (int r = 0; r < 4; r++) mrow[r] = fmaxf(mrow[r], __shfl_xor(mrow[r], off));
            float rs[4];
#pragma unroll
            for (int r = 0; r < 4; r++) {
                float mn = fmaxf(m_i[mt][r], mrow[r]);
                float alpha = __expf(m_i[mt][r] - mn);
                m_i[mt][r] = mn;
                l_i[mt][r] *= alpha;
                rs[r] = 0.f;
#pragma unroll
                for (int dt = 0; dt < 8; dt++) oa[mt][dt][r] *= alpha;
            }
#pragma unroll
            for (int nt = 0; nt < 4; nt++)
#pragma unroll
                for (int r = 0; r < 4; r++) {
                    float pw = __expf(sa[mt][nt][r] - m_i[mt][r]);
                    rs[r] += pw;
                    Pls[pbase + (mt * 16 + quad * 4 + r) * 80 + nt * 16 + lr] = f2bf(pw);
                }
#pragma unroll
            for (int off = 1; off < 16; off <<= 1)
#pragma unroll
                for (int r = 0; r < 4; r++) rs[r] += __shfl_xor(rs[r], off);
#pragma unroll
            for (int r = 0; r < 4; r++) l_i[mt][r] += rs[r];
        }

        // O += P V  (pf via per-wave LDS; vf pre-loaded)
#pragma unroll
        for (int ks = 0; ks < 2; ks++) {
            frag_ab pf[2];
#pragma unroll
            for (int mt = 0; mt < 2; mt++)
                pf[mt] = *(const frag_ab*)&Pls[pbase + (mt * 16 + lr) * 80 + ks * 32 + quad * 8];
#pragma unroll
            for (int dt = 0; dt < 8; dt++) {
                oa[0][dt] = __builtin_amdgcn_mfma_f32_16x16x32_bf16(pf[0], vf[ks][dt], oa[0][dt], 0, 0, 0);
                oa[1][dt] = __builtin_amdgcn_mfma_f32_16x16x32_bf16(pf[1], vf[ks][dt], oa[1][dt], 0, 0, 0);
            }
        }
    }

    // ---- flash-decoding merge across the 4 waves ----
    // publish per-wave (m, l); lanes lr==0 (one per quad) cover rows quad*4+r
    if (lr == 0) {
#pragma unroll
        for (int mt = 0; mt < 2; mt++)
#pragma unroll
            for (int r = 0; r < 4; r++) {
                mlb[wave][mt][quad * 4 + r][0] = m_i[mt][r];
                mlb[wave][mt][quad * 4 + r][1] = l_i[mt][r];
            }
    }
    __syncthreads();
    // global max + merged denom; rescale own accumulator in-reg
    float inv[2][4];
#pragma unroll
    for (int mt = 0; mt < 2; mt++)
#pragma unroll
        for (int r = 0; r < 4; r++) {
            int row = quad * 4 + r;
            float m0 = mlb[0][mt][row][0], m1 = mlb[1][mt][row][0];
            float m2 = mlb[2][mt][row][0], m3 = mlb[3][mt][row][0];
            float ms = fmaxf(fmaxf(m0, m1), fmaxf(m2, m3));
            float ls = mlb[0][mt][row][1] * __expf(m0 - ms) + mlb[1][mt][row][1] * __expf(m1 - ms)
                     + mlb[2][mt][row][1] * __expf(m2 - ms) + mlb[3][mt][row][1] * __expf(m3 - ms);
            inv[mt][r] = 1.f / ls;
            float alpha = __expf(m_i[mt][r] - ms);   // 0 for waves with no work
#pragma unroll
            for (int dt = 0; dt < 8; dt++) oa[mt][dt][r] *= alpha;
        }
    // serialized accumulate into macc (float4 rows: [mt][dt][col=lr][row quad*4..+3])
    for (int w = 0; w < 4; w++) {
        if (wave == w) {
#pragma unroll
            for (int mt = 0; mt < 2; mt++)
#pragma unroll
                for (int dt = 0; dt < 8; dt++) {
                    frag_cd* p = (frag_cd*)&macc[mt][dt][lr][quad * 4];
                    if (w == 0) *p = oa[mt][dt];
                    else {
                        frag_cd o = *p;
#pragma unroll
                        for (int r = 0; r < 4; r++) o[r] += oa[mt][dt][r];
                        *p = o;
                    }
                }
        }
        __syncthreads();
    }
    // cooperative epilogue: wave handles dt = 2*wave, 2*wave+1
#pragma unroll
    for (int mt = 0; mt < 2; mt++)
#pragma unroll
        for (int dto = 0; dto < 2; dto++) {
            int dt = wave * 2 + dto;
            frag_cd v = *(const frag_cd*)&macc[mt][dt][lr][quad * 4];
#pragma unroll
            for (int r = 0; r < 4; r++) {
                int s = q0 + mt * 16 + quad * 4 + r;
                O[((long)b * S_LEN + s) * (NH * HD) + h * HD + dt * 16 + lr] =
                    f2bf(v[r] * inv[mt][r]);
            }
        }
}

extern "C" void kernel_launch(void* const* d_in, const int* in_sizes, int n_in,
                              void* d_out, int out_size, void* d_ws, size_t ws_size,
                              hipStream_t stream) {
    const float* hs  = (const float*)d_in[0];
    const float* q_w = (const float*)d_in[1];
    const float* k_w = (const float*)d_in[2];
    const float* v_w = (const float*)d_in[3];
    const float* o_w = (const float*)d_in[4];
    const float* qnw = (const float*)d_in[5];
    const float* knw = (const float*)d_in[6];
    float* out = (float*)d_out;

    // Workspace (72 MiB, live ranges stream-serialized & disjoint):
    //   [ 0,16M) hs_bf : hidden bf16; later attn-out bf16
    //   [16,24M) wbuf  : weights bf16 (Q 8M; then KV 4M; then O 8M)
    //   [24,56M) gout  : fp32 GEMM out (Q all 32M; KV uses [24,40) only)
    //   [40,44M) Kr    : bf16 [b][4][s][128]
    //   [44,48M) Vt    : bf16 [b][4][d][s] transposed
    //   [56,72M) Qr    : bf16 [b][16][s][128]
    char* ws = (char*)d_ws;
    u16* hs_bf  = (u16*)(ws);
    u16* wbuf   = (u16*)(ws + (16ul << 20));
    float* gout = (float*)(ws + (24ul << 20));
    u16* Kr     = (u16*)(ws + (40ul << 20));
    u16* Vt     = (u16*)(ws + (44ul << 20));
    u16* Qr     = (u16*)(ws + (56ul << 20));
    (void)ws_size; (void)in_sizes; (void)n_in; (void)out_size;

    // hidden -> bf16
    conv_f32_bf16<<<(MROWS * HID / 4 + 255) / 256, 256, 0, stream>>>(hs, hs_bf, MROWS * HID / 4);

    // Q = hs @ q_w^T ; rmsnorm + rope
    conv_f32_bf16<<<(HID * HID / 4 + 255) / 256, 256, 0, stream>>>(q_w, wbuf, HID * HID / 4);
    dim3 gq(MROWS / 128, HID / 128);
    gemm_bt<<<gq, 256, 0, stream>>>(hs_bf, wbuf, gout, MROWS, HID, HID);
    rope_norm<<<MROWS, 256, 0, stream>>>(gout, Qr, qnw, NH, HID, 0);

    // K|V fused projection: wbuf rows [0,512)=k_w, [512,1024)=v_w; N=1024
    conv_f32_bf16<<<(NKV * HD * HID / 4 + 255) / 256, 256, 0, stream>>>(k_w, wbuf, NKV * HD * HID / 4);
    conv_f32_bf16<<<(NKV * HD * HID / 4 + 255) / 256, 256, 0, stream>>>(v_w, wbuf + NKV * HD * HID, NKV * HD * HID / 4);
    dim3 gkv(MROWS / 128, (2 * NKV * HD) / 128);
    gemm_bt<<<gkv, 256, 0, stream>>>(hs_bf, wbuf, gout, MROWS, 2 * NKV * HD, HID);
    rope_norm<<<MROWS, 256, 0, stream>>>(gout, Kr, knw, NKV, 2 * NKV * HD, 0);
    pack_vt<<<BATCH * NKV * (S_LEN / 64), 256, 0, stream>>>(gout, Vt, 2 * NKV * HD, NKV * HD);

    // attention -> hs_bf  (grid = 64 tiles x 32 bh = 2048, 4-wave split-K blocks)
    flash_attn<<<2048, 256, 0, stream>>>(Qr, Kr, Vt, hs_bf);

    // out = attn @ o_w^T
    conv_f32_bf16<<<(HID * HID / 4 + 255) / 256, 256, 0, stream>>>(o_w, wbuf, HID * HID / 4);
    gemm_bt<<<gq, 256, 0, stream>>>(hs_bf, wbuf, out, MROWS, HID, HID);
}